// Round 4
// baseline (108.811 us; speedup 1.0000x reference)
//
#include <hip/hip_runtime.h>
#include <hip/hip_bf16.h>

#define N_ 4096
#define D_ 768
#define NCLS 128
#define BM 256
#define BN 256
#define KSTEP 32
#define NSTEP 24  // D_/KSTEP

typedef __bf16 bf16x8 __attribute__((ext_vector_type(8)));
typedef float f32x16 __attribute__((ext_vector_type(16)));

#define SBAR() asm volatile("s_barrier" ::: "memory")
#define VMWAIT12() asm volatile("s_waitcnt vmcnt(12)" ::: "memory")
#define LGKM0() asm volatile("s_waitcnt lgkmcnt(0)" ::: "memory")

__device__ __forceinline__ void gload16(const unsigned short* g, unsigned short* l) {
  __builtin_amdgcn_global_load_lds(
      (const __attribute__((address_space(1))) unsigned int*)g,
      (__attribute__((address_space(3))) unsigned int*)l, 16, 0, 0);
}

// Normalize both embedding matrices (blocks [0,N) -> img, [N,2N) -> txt).
__global__ __launch_bounds__(192) void normalize_kernel(
    const float* __restrict__ img, const float* __restrict__ txt,
    __hip_bfloat16* __restrict__ img_nb, __hip_bfloat16* __restrict__ txt_nb) {
  int b = blockIdx.x;
  const float* s;
  __hip_bfloat16* d;
  if (b < N_) {
    s = img + (size_t)b * D_;
    d = img_nb + (size_t)b * D_;
  } else {
    s = txt + (size_t)(b - N_) * D_;
    d = txt_nb + (size_t)(b - N_) * D_;
  }
  int tid = threadIdx.x;
  float4 v = ((const float4*)s)[tid];
  float ss = v.x * v.x + v.y * v.y + v.z * v.z + v.w * v.w;
#pragma unroll
  for (int m = 32; m; m >>= 1) ss += __shfl_xor(ss, m);
  __shared__ float wsum[3];
  int lane = tid & 63, w = tid >> 6;
  if (lane == 0) wsum[w] = ss;
  __syncthreads();
  float inv = 1.0f / fmaxf(sqrtf(wsum[0] + wsum[1] + wsum[2]), 1e-8f);
  ushort4 o;
  o.x = __bfloat16_as_ushort(__float2bfloat16(v.x * inv));
  o.y = __bfloat16_as_ushort(__float2bfloat16(v.y * inv));
  o.z = __bfloat16_as_ushort(__float2bfloat16(v.z * inv));
  o.w = __bfloat16_as_ushort(__float2bfloat16(v.w * inv));
  ((ushort4*)d)[tid] = o;
}

// 256x256-tile GEMM, 4-slot LDS K-ring, counted vmcnt(12) pipeline (T3+T4+T5),
// fused exp-sum epilogue. LDS per slot per matrix: chunk-linear [g=k/8][row][8 bf16].
__global__ __launch_bounds__(512, 2) void gemm_epi_kernel(
    const unsigned short* __restrict__ A, const unsigned short* __restrict__ B,
    const int* __restrict__ labels, float* __restrict__ row_part,
    float* __restrict__ col_part, float* __restrict__ S_part) {
  __shared__ __align__(16) unsigned short AS[4][8192];  // 4 ring slots x 16KB
  __shared__ __align__(16) unsigned short BS[4][8192];
  __shared__ int labR[BM], labC[BN];
  __shared__ float rbuf[4][BM], cbuf[2][BN];
  __shared__ float sbuf[8];

  const int bx = blockIdx.x, by = blockIdx.y;
  const int tid = threadIdx.x;
  const int lane = tid & 63, w = tid >> 6;
  const int wr = w >> 2, wc = w & 3;   // 2x4 wave grid; wave owns 128x64 output
  const int ln = lane & 31, h = lane >> 5;
  const int rowBase = by * BM, colBase = bx * BN;

  if (tid < BM) labR[tid] = labels[rowBase + tid];
  else labC[tid - BM] = labels[colBase + tid - BM];

  // staging: thread covers chunks c0 = w*64+lane, c1 = 512+w*64+lane (1024 chunks/matrix/step)
  const int c0 = w * 64 + lane, c1 = 512 + w * 64 + lane;
  const int db0 = (w * 64) * 8, db1 = (512 + w * 64) * 8;  // wave-uniform LDS dests
  const unsigned short* sA0 = A + (size_t)(rowBase + (c0 & 255)) * D_ + (c0 >> 8) * 8;
  const unsigned short* sA1 = A + (size_t)(rowBase + (c1 & 255)) * D_ + (c1 >> 8) * 8;
  const unsigned short* sB0 = B + (size_t)(colBase + (c0 & 255)) * D_ + (c0 >> 8) * 8;
  const unsigned short* sB1 = B + (size_t)(colBase + (c1 & 255)) * D_ + (c1 >> 8) * 8;

  // prologue: stage steps 0,1,2 into slots 0,1,2 (12 loads in flight)
#pragma unroll
  for (int p = 0; p < 3; ++p) {
    const int kk = p * KSTEP;
    gload16(sA0 + kk, &AS[p][db0]);
    gload16(sA1 + kk, &AS[p][db1]);
    gload16(sB0 + kk, &BS[p][db0]);
    gload16(sB1 + kk, &BS[p][db1]);
  }

  f32x16 acc[4][2] = {};
  const int aoff = (h * 256 + wr * 128 + ln) * 8;  // + ks*4096 + mb*256
  const int boff = (h * 256 + wc * 64 + ln) * 8;   // + ks*4096 + nb*256

#pragma unroll 4
  for (int u = 0; u < NSTEP; ++u) {
    SBAR();  // all waves finished step u-1 reads -> slot (u+3)&3 is free to overwrite
    {
      const int su = (u + 3 < NSTEP) ? u + 3 : NSTEP - 1;  // tail: clamped dummy restage
      const int kk = su * KSTEP;
      const int sl = (u + 3) & 3;
      gload16(sA0 + kk, &AS[sl][db0]);
      gload16(sA1 + kk, &AS[sl][db1]);
      gload16(sB0 + kk, &BS[sl][db0]);
      gload16(sB1 + kk, &BS[sl][db1]);
    }
    VMWAIT12();  // keep 3 stage-units (12 loads) in flight; step u's 4 chunks landed
    SBAR();      // every wave's step-u chunks landed: slot u&3 fully valid
    const unsigned short* as_ = AS[u & 3];
    const unsigned short* bs_ = BS[u & 3];
    bf16x8 af[4][2], bfv[2][2];
#pragma unroll
    for (int ks = 0; ks < 2; ++ks) {
#pragma unroll
      for (int mb = 0; mb < 4; ++mb)
        af[mb][ks] = *(const bf16x8*)&as_[aoff + ks * 4096 + mb * 256];
#pragma unroll
      for (int nb = 0; nb < 2; ++nb)
        bfv[nb][ks] = *(const bf16x8*)&bs_[boff + ks * 4096 + nb * 256];
    }
    __builtin_amdgcn_s_setprio(1);
#pragma unroll
    for (int ks = 0; ks < 2; ++ks)
#pragma unroll
      for (int mb = 0; mb < 4; ++mb)
#pragma unroll
        for (int nb = 0; nb < 2; ++nb)
          acc[mb][nb] = __builtin_amdgcn_mfma_f32_32x32x16_bf16(
              af[mb][ks], bfv[nb][ks], acc[mb][nb], 0, 0, 0);
    __builtin_amdgcn_s_setprio(0);
    LGKM0();  // my ds_reads drained before signaling the next entry barrier
  }

  // epilogue: C/D layout 32x32: row=(r&3)+8*(r>>2)+4*h (+mb*32+wr*128), col=ln (+nb*32+wc*64)
  const float scale = 14.285714285714286f;  // 1/0.07
  const int lc0 = labC[wc * 64 + ln], lc1 = labC[wc * 64 + 32 + ln];
  float sPart = 0.f;
  float colAcc[2] = {0.f, 0.f};
#pragma unroll
  for (int mb = 0; mb < 4; ++mb) {
#pragma unroll
    for (int r = 0; r < 16; ++r) {
      const int row = wr * 128 + mb * 32 + (r & 3) + ((r >> 2) * 8) + h * 4;
      const int lr = labR[row];
      float v0 = acc[mb][0][r] * scale;
      float v1 = acc[mb][1][r] * scale;
      float e0 = __expf(v0), e1 = __expf(v1);
      float rowv = e0 + e1;
      colAcc[0] += e0;
      colAcc[1] += e1;
      if (lr == lc0) sPart += v0;
      if (lr == lc1) sPart += v1;
      rowv += __shfl_xor(rowv, 1);
      rowv += __shfl_xor(rowv, 2);
      rowv += __shfl_xor(rowv, 4);
      rowv += __shfl_xor(rowv, 8);
      rowv += __shfl_xor(rowv, 16);
      if (ln == 0) rbuf[wc][row] = rowv;
    }
  }
#pragma unroll
  for (int nb = 0; nb < 2; ++nb) {
    float x = colAcc[nb] + __shfl_xor(colAcc[nb], 32);
    if (h == 0) cbuf[wr][wc * 64 + nb * 32 + ln] = x;
  }
  float s = sPart;
#pragma unroll
  for (int m = 32; m; m >>= 1) s += __shfl_xor(s, m);
  if (lane == 0) sbuf[w] = s;
  __syncthreads();
  if (tid < BM) {
    row_part[(size_t)bx * N_ + rowBase + tid] =
        rbuf[0][tid] + rbuf[1][tid] + rbuf[2][tid] + rbuf[3][tid];
  } else {
    int c = tid - BM;
    col_part[(size_t)by * N_ + colBase + c] = cbuf[0][c] + cbuf[1][c];
  }
  if (tid == 0)
    S_part[by * 16 + bx] =
        sbuf[0] + sbuf[1] + sbuf[2] + sbuf[3] + sbuf[4] + sbuf[5] + sbuf[6] + sbuf[7];
}

// Per-block local histogram; partials out (no atomics, no memset needed)
__global__ __launch_bounds__(256) void reduce_kernel(
    const float* __restrict__ row_part, const float* __restrict__ col_part,
    const float* __restrict__ S_part, const int* __restrict__ labels,
    double* __restrict__ partials) {
  __shared__ int hist[NCLS];
  int tid = threadIdx.x;
  if (tid < NCLS) hist[tid] = 0;
  __syncthreads();
  for (int j = tid; j < N_; j += 256) atomicAdd(&hist[labels[j]], 1);
  __syncthreads();

  int i = blockIdx.x * 256 + tid;  // 0..4095
  float rs = 0.f, cs = 0.f;
#pragma unroll
  for (int b = 0; b < 16; ++b) {
    rs += row_part[(size_t)b * N_ + i];
    cs += col_part[(size_t)b * N_ + i];
  }
  int cnt = hist[labels[i]];
  double term = (double)cnt * ((double)logf(rs) + (double)logf(cs));
  double sterm = (i < 256) ? (double)S_part[i] : 0.0;
#pragma unroll
  for (int m = 32; m; m >>= 1) {
    term += __shfl_xor(term, m);
    sterm += __shfl_xor(sterm, m);
  }
  __shared__ double tbuf[4], sb[4];
  int lane = tid & 63, w = tid >> 6;
  if (lane == 0) { tbuf[w] = term; sb[w] = sterm; }
  __syncthreads();
  if (tid == 0) {
    partials[blockIdx.x] = tbuf[0] + tbuf[1] + tbuf[2] + tbuf[3];
    partials[16 + blockIdx.x] = sb[0] + sb[1] + sb[2] + sb[3];
  }
}

__global__ void final_kernel(const double* __restrict__ partials, float* __restrict__ out) {
  double t = 0.0, s = 0.0;
#pragma unroll
  for (int i = 0; i < 16; ++i) {
    t += partials[i];
    s += partials[16 + i];
  }
  out[0] = (float)((t - 2.0 * s) / (2.0 * (double)N_));
}

extern "C" void kernel_launch(void* const* d_in, const int* in_sizes, int n_in,
                              void* d_out, int out_size, void* d_ws, size_t ws_size,
                              hipStream_t stream) {
  const float* img = (const float*)d_in[0];
  const float* txt = (const float*)d_in[1];
  const int* labels = (const int*)d_in[2];
  float* out = (float*)d_out;
  char* ws = (char*)d_ws;

  // workspace layout (bytes)
  __hip_bfloat16* img_nb = (__hip_bfloat16*)(ws);             //  6,291,456
  __hip_bfloat16* txt_nb = (__hip_bfloat16*)(ws + 6291456);   //  6,291,456
  float* row_part = (float*)(ws + 12582912);                  //    262,144 (16 x 4096)
  float* col_part = (float*)(ws + 12845056);                  //    262,144
  float* S_part = (float*)(ws + 13107200);                    //      1,024
  double* partials = (double*)(ws + 13108224);                //        256

  normalize_kernel<<<2 * N_, 192, 0, stream>>>(img, txt, img_nb, txt_nb);
  gemm_epi_kernel<<<dim3(16, 16), 512, 0, stream>>>(
      (const unsigned short*)img_nb, (const unsigned short*)txt_nb, labels,
      row_part, col_part, S_part);
  reduce_kernel<<<16, 256, 0, stream>>>(row_part, col_part, S_part, labels, partials);
  final_kernel<<<1, 1, 0, stream>>>(partials, out);
}

// Round 5
// 108.513 us; speedup vs baseline: 1.0027x; 1.0027x over previous
//
#include <hip/hip_runtime.h>
#include <hip/hip_bf16.h>

#define N_ 4096
#define D_ 768
#define NCLS 128
#define BM 256
#define BN 256
#define KSTEP 32
#define NSTEP 24  // D_/KSTEP

typedef __bf16 bf16x8 __attribute__((ext_vector_type(8)));
typedef float f32x16 __attribute__((ext_vector_type(16)));

#define SBAR() asm volatile("s_barrier" ::: "memory")
#define VMWAIT12() asm volatile("s_waitcnt vmcnt(12)" ::: "memory")
#define LGKM0() asm volatile("s_waitcnt lgkmcnt(0)" ::: "memory")

__device__ __forceinline__ void gload16(const unsigned short* g, unsigned short* l) {
  __builtin_amdgcn_global_load_lds(
      (const __attribute__((address_space(1))) unsigned int*)g,
      (__attribute__((address_space(3))) unsigned int*)l, 16, 0, 0);
}

// Normalize both embedding matrices (blocks [0,N) -> img, [N,2N) -> txt).
__global__ __launch_bounds__(192) void normalize_kernel(
    const float* __restrict__ img, const float* __restrict__ txt,
    __hip_bfloat16* __restrict__ img_nb, __hip_bfloat16* __restrict__ txt_nb) {
  int b = blockIdx.x;
  const float* s;
  __hip_bfloat16* d;
  if (b < N_) {
    s = img + (size_t)b * D_;
    d = img_nb + (size_t)b * D_;
  } else {
    s = txt + (size_t)(b - N_) * D_;
    d = txt_nb + (size_t)(b - N_) * D_;
  }
  int tid = threadIdx.x;
  float4 v = ((const float4*)s)[tid];
  float ss = v.x * v.x + v.y * v.y + v.z * v.z + v.w * v.w;
#pragma unroll
  for (int m = 32; m; m >>= 1) ss += __shfl_xor(ss, m);
  __shared__ float wsum[3];
  int lane = tid & 63, w = tid >> 6;
  if (lane == 0) wsum[w] = ss;
  __syncthreads();
  float inv = 1.0f / fmaxf(sqrtf(wsum[0] + wsum[1] + wsum[2]), 1e-8f);
  ushort4 o;
  o.x = __bfloat16_as_ushort(__float2bfloat16(v.x * inv));
  o.y = __bfloat16_as_ushort(__float2bfloat16(v.y * inv));
  o.z = __bfloat16_as_ushort(__float2bfloat16(v.z * inv));
  o.w = __bfloat16_as_ushort(__float2bfloat16(v.w * inv));
  ((ushort4*)d)[tid] = o;
}

// 256x256-tile GEMM, 4-slot LDS K-ring, counted vmcnt(12) pipeline (T3+T4+T5),
// fused exp-sum epilogue. LDS per slot per matrix: chunk-linear [g=k/8][row][8 bf16].
// __launch_bounds__(512, 1): 256-VGPR budget -- acc[4][2] f32x16 must stay in regs
// (512,2) capped VGPR at 128 and spilled the accumulators (r4: WRITE_SIZE 43.5MB).
__global__ __launch_bounds__(512, 1) void gemm_epi_kernel(
    const unsigned short* __restrict__ A, const unsigned short* __restrict__ B,
    const int* __restrict__ labels, float* __restrict__ row_part,
    float* __restrict__ col_part, float* __restrict__ S_part) {
  __shared__ __align__(16) unsigned short AS[4][8192];  // 4 ring slots x 16KB
  __shared__ __align__(16) unsigned short BS[4][8192];
  __shared__ int labR[BM], labC[BN];
  __shared__ float rbuf[4][BM], cbuf[2][BN];
  __shared__ float sbuf[8];

  const int bx = blockIdx.x, by = blockIdx.y;
  const int tid = threadIdx.x;
  const int lane = tid & 63, w = tid >> 6;
  const int wr = w >> 2, wc = w & 3;   // 2x4 wave grid; wave owns 128x64 output
  const int ln = lane & 31, h = lane >> 5;
  const int rowBase = by * BM, colBase = bx * BN;

  if (tid < BM) labR[tid] = labels[rowBase + tid];
  else labC[tid - BM] = labels[colBase + tid - BM];

  // staging: thread covers chunks c0 = w*64+lane, c1 = 512+w*64+lane (1024 chunks/matrix/step)
  const int c0 = w * 64 + lane, c1 = 512 + w * 64 + lane;
  const int db0 = (w * 64) * 8, db1 = (512 + w * 64) * 8;  // wave-uniform LDS dests
  const unsigned short* sA0 = A + (size_t)(rowBase + (c0 & 255)) * D_ + (c0 >> 8) * 8;
  const unsigned short* sA1 = A + (size_t)(rowBase + (c1 & 255)) * D_ + (c1 >> 8) * 8;
  const unsigned short* sB0 = B + (size_t)(colBase + (c0 & 255)) * D_ + (c0 >> 8) * 8;
  const unsigned short* sB1 = B + (size_t)(colBase + (c1 & 255)) * D_ + (c1 >> 8) * 8;

  // prologue: stage steps 0,1,2 into slots 0,1,2 (12 loads in flight)
#pragma unroll
  for (int p = 0; p < 3; ++p) {
    const int kk = p * KSTEP;
    gload16(sA0 + kk, &AS[p][db0]);
    gload16(sA1 + kk, &AS[p][db1]);
    gload16(sB0 + kk, &BS[p][db0]);
    gload16(sB1 + kk, &BS[p][db1]);
  }

  f32x16 acc[4][2] = {};
  const int aoff = (h * 256 + wr * 128 + ln) * 8;  // + ks*4096 + mb*256
  const int boff = (h * 256 + wc * 64 + ln) * 8;   // + ks*4096 + nb*256

#pragma unroll 4
  for (int u = 0; u < NSTEP; ++u) {
    SBAR();  // all waves finished step u-1 reads -> slot (u+3)&3 is free to overwrite
    {
      const int su = (u + 3 < NSTEP) ? u + 3 : NSTEP - 1;  // tail: clamped dummy restage
      const int kk = su * KSTEP;
      const int sl = (u + 3) & 3;
      gload16(sA0 + kk, &AS[sl][db0]);
      gload16(sA1 + kk, &AS[sl][db1]);
      gload16(sB0 + kk, &BS[sl][db0]);
      gload16(sB1 + kk, &BS[sl][db1]);
    }
    VMWAIT12();  // keep 3 stage-units (12 loads) in flight; step u's 4 chunks landed
    SBAR();      // every wave's step-u chunks landed: slot u&3 fully valid
    const unsigned short* as_ = AS[u & 3];
    const unsigned short* bs_ = BS[u & 3];
    bf16x8 af[4][2], bfv[2][2];
#pragma unroll
    for (int ks = 0; ks < 2; ++ks) {
#pragma unroll
      for (int mb = 0; mb < 4; ++mb)
        af[mb][ks] = *(const bf16x8*)&as_[aoff + ks * 4096 + mb * 256];
#pragma unroll
      for (int nb = 0; nb < 2; ++nb)
        bfv[nb][ks] = *(const bf16x8*)&bs_[boff + ks * 4096 + nb * 256];
    }
    __builtin_amdgcn_s_setprio(1);
#pragma unroll
    for (int ks = 0; ks < 2; ++ks)
#pragma unroll
      for (int mb = 0; mb < 4; ++mb)
#pragma unroll
        for (int nb = 0; nb < 2; ++nb)
          acc[mb][nb] = __builtin_amdgcn_mfma_f32_32x32x16_bf16(
              af[mb][ks], bfv[nb][ks], acc[mb][nb], 0, 0, 0);
    __builtin_amdgcn_s_setprio(0);
    LGKM0();  // my ds_reads drained before signaling the next entry barrier
  }

  // epilogue: C/D layout 32x32: row=(r&3)+8*(r>>2)+4*h (+mb*32+wr*128), col=ln (+nb*32+wc*64)
  const float scale = 14.285714285714286f;  // 1/0.07
  const int lc0 = labC[wc * 64 + ln], lc1 = labC[wc * 64 + 32 + ln];
  float sPart = 0.f;
  float colAcc[2] = {0.f, 0.f};
#pragma unroll
  for (int mb = 0; mb < 4; ++mb) {
#pragma unroll
    for (int r = 0; r < 16; ++r) {
      const int row = wr * 128 + mb * 32 + (r & 3) + ((r >> 2) * 8) + h * 4;
      const int lr = labR[row];
      float v0 = acc[mb][0][r] * scale;
      float v1 = acc[mb][1][r] * scale;
      float e0 = __expf(v0), e1 = __expf(v1);
      float rowv = e0 + e1;
      colAcc[0] += e0;
      colAcc[1] += e1;
      if (lr == lc0) sPart += v0;
      if (lr == lc1) sPart += v1;
      rowv += __shfl_xor(rowv, 1);
      rowv += __shfl_xor(rowv, 2);
      rowv += __shfl_xor(rowv, 4);
      rowv += __shfl_xor(rowv, 8);
      rowv += __shfl_xor(rowv, 16);
      if (ln == 0) rbuf[wc][row] = rowv;
    }
  }
#pragma unroll
  for (int nb = 0; nb < 2; ++nb) {
    float x = colAcc[nb] + __shfl_xor(colAcc[nb], 32);
    if (h == 0) cbuf[wr][wc * 64 + nb * 32 + ln] = x;
  }
  float s = sPart;
#pragma unroll
  for (int m = 32; m; m >>= 1) s += __shfl_xor(s, m);
  if (lane == 0) sbuf[w] = s;
  __syncthreads();
  if (tid < BM) {
    row_part[(size_t)bx * N_ + rowBase + tid] =
        rbuf[0][tid] + rbuf[1][tid] + rbuf[2][tid] + rbuf[3][tid];
  } else {
    int c = tid - BM;
    col_part[(size_t)by * N_ + colBase + c] = cbuf[0][c] + cbuf[1][c];
  }
  if (tid == 0)
    S_part[by * 16 + bx] =
        sbuf[0] + sbuf[1] + sbuf[2] + sbuf[3] + sbuf[4] + sbuf[5] + sbuf[6] + sbuf[7];
}

// Per-block local histogram; partials out (no atomics, no memset needed)
__global__ __launch_bounds__(256) void reduce_kernel(
    const float* __restrict__ row_part, const float* __restrict__ col_part,
    const float* __restrict__ S_part, const int* __restrict__ labels,
    double* __restrict__ partials) {
  __shared__ int hist[NCLS];
  int tid = threadIdx.x;
  if (tid < NCLS) hist[tid] = 0;
  __syncthreads();
  for (int j = tid; j < N_; j += 256) atomicAdd(&hist[labels[j]], 1);
  __syncthreads();

  int i = blockIdx.x * 256 + tid;  // 0..4095
  float rs = 0.f, cs = 0.f;
#pragma unroll
  for (int b = 0; b < 16; ++b) {
    rs += row_part[(size_t)b * N_ + i];
    cs += col_part[(size_t)b * N_ + i];
  }
  int cnt = hist[labels[i]];
  double term = (double)cnt * ((double)logf(rs) + (double)logf(cs));
  double sterm = (i < 256) ? (double)S_part[i] : 0.0;
#pragma unroll
  for (int m = 32; m; m >>= 1) {
    term += __shfl_xor(term, m);
    sterm += __shfl_xor(sterm, m);
  }
  __shared__ double tbuf[4], sb[4];
  int lane = tid & 63, w = tid >> 6;
  if (lane == 0) { tbuf[w] = term; sb[w] = sterm; }
  __syncthreads();
  if (tid == 0) {
    partials[blockIdx.x] = tbuf[0] + tbuf[1] + tbuf[2] + tbuf[3];
    partials[16 + blockIdx.x] = sb[0] + sb[1] + sb[2] + sb[3];
  }
}

__global__ void final_kernel(const double* __restrict__ partials, float* __restrict__ out) {
  double t = 0.0, s = 0.0;
#pragma unroll
  for (int i = 0; i < 16; ++i) {
    t += partials[i];
    s += partials[16 + i];
  }
  out[0] = (float)((t - 2.0 * s) / (2.0 * (double)N_));
}

extern "C" void kernel_launch(void* const* d_in, const int* in_sizes, int n_in,
                              void* d_out, int out_size, void* d_ws, size_t ws_size,
                              hipStream_t stream) {
  const float* img = (const float*)d_in[0];
  const float* txt = (const float*)d_in[1];
  const int* labels = (const int*)d_in[2];
  float* out = (float*)d_out;
  char* ws = (char*)d_ws;

  // workspace layout (bytes)
  __hip_bfloat16* img_nb = (__hip_bfloat16*)(ws);             //  6,291,456
  __hip_bfloat16* txt_nb = (__hip_bfloat16*)(ws + 6291456);   //  6,291,456
  float* row_part = (float*)(ws + 12582912);                  //    262,144 (16 x 4096)
  float* col_part = (float*)(ws + 12845056);                  //    262,144
  float* S_part = (float*)(ws + 13107200);                    //      1,024
  double* partials = (double*)(ws + 13108224);                //        256

  normalize_kernel<<<2 * N_, 192, 0, stream>>>(img, txt, img_nb, txt_nb);
  gemm_epi_kernel<<<dim3(16, 16), 512, 0, stream>>>(
      (const unsigned short*)img_nb, (const unsigned short*)txt_nb, labels,
      row_part, col_part, S_part);
  reduce_kernel<<<16, 256, 0, stream>>>(row_part, col_part, S_part, labels, partials);
  final_kernel<<<1, 1, 0, stream>>>(partials, out);
}

// Round 6
// 83.749 us; speedup vs baseline: 1.2993x; 1.2957x over previous
//
#include <hip/hip_runtime.h>
#include <hip/hip_bf16.h>

#define N_ 4096
#define D_ 768
#define NCLS 128
#define BM 128
#define BN 128
#define BK 32
#define NSTEP 24  // D_/BK

typedef __bf16 bf16x8 __attribute__((ext_vector_type(8)));
typedef float f32x4 __attribute__((ext_vector_type(4)));

#define SBAR() asm volatile("s_barrier" ::: "memory")
#define VMWAIT8() asm volatile("s_waitcnt vmcnt(8)" ::: "memory")
#define LGKM0() asm volatile("s_waitcnt lgkmcnt(0)" ::: "memory")

__device__ __forceinline__ void gload16(const unsigned short* g, unsigned short* l) {
  __builtin_amdgcn_global_load_lds(
      (const __attribute__((address_space(1))) unsigned int*)g,
      (__attribute__((address_space(3))) unsigned int*)l, 16, 0, 0);
}

// Normalize both embedding matrices (blocks [0,N) -> img, [N,2N) -> txt).
__global__ __launch_bounds__(192) void normalize_kernel(
    const float* __restrict__ img, const float* __restrict__ txt,
    __hip_bfloat16* __restrict__ img_nb, __hip_bfloat16* __restrict__ txt_nb) {
  int b = blockIdx.x;
  const float* s;
  __hip_bfloat16* d;
  if (b < N_) {
    s = img + (size_t)b * D_;
    d = img_nb + (size_t)b * D_;
  } else {
    s = txt + (size_t)(b - N_) * D_;
    d = txt_nb + (size_t)(b - N_) * D_;
  }
  int tid = threadIdx.x;
  float4 v = ((const float4*)s)[tid];
  float ss = v.x * v.x + v.y * v.y + v.z * v.z + v.w * v.w;
#pragma unroll
  for (int m = 32; m; m >>= 1) ss += __shfl_xor(ss, m);
  __shared__ float wsum[3];
  int lane = tid & 63, w = tid >> 6;
  if (lane == 0) wsum[w] = ss;
  __syncthreads();
  float inv = 1.0f / fmaxf(sqrtf(wsum[0] + wsum[1] + wsum[2]), 1e-8f);
  ushort4 o;
  o.x = __bfloat16_as_ushort(__float2bfloat16(v.x * inv));
  o.y = __bfloat16_as_ushort(__float2bfloat16(v.y * inv));
  o.z = __bfloat16_as_ushort(__float2bfloat16(v.z * inv));
  o.w = __bfloat16_as_ushort(__float2bfloat16(v.w * inv));
  ((ushort4*)d)[tid] = o;
}

// 128x128-tile GEMM (r2's lean codegen: 4 waves, 16x16x32 MFMA, acc[4][4] f32x4),
// 3-slot LDS K-ring with counted vmcnt(8): prefetch 2 steps ahead, loads stay in
// flight across barriers (T4). LDS per slot per matrix: chunk-linear [g=k/8][row][8].
// NO unroll on the main loop (r4/r5 lesson: unrolled bodies ballooned live ranges
// -> scratch spill, WRITE_SIZE 43.5MB).
__global__ __launch_bounds__(256) void gemm_epi_kernel(
    const unsigned short* __restrict__ A, const unsigned short* __restrict__ B,
    const int* __restrict__ labels, float* __restrict__ row_part,
    float* __restrict__ col_part, float* __restrict__ S_part) {
  __shared__ __align__(16) unsigned short AS[3][4096];  // 3 ring slots x 8KB
  __shared__ __align__(16) unsigned short BS[3][4096];
  __shared__ int labR[BM], labC[BN];
  __shared__ float rbuf[2][BM], cbuf[2][BN];
  __shared__ float sbuf[4];

  const int bx = blockIdx.x, by = blockIdx.y;
  const int tid = threadIdx.x;
  const int lane = tid & 63, wave = tid >> 6;
  const int wr = wave >> 1, wc = wave & 1;
  const int g = lane >> 4, fr = lane & 15;
  const int rowBase = by * BM, colBase = bx * BN;

  if (tid < BM) labR[tid] = labels[rowBase + tid];
  else labC[tid - BM] = labels[colBase + tid - BM];

  // staging coordinates (fixed across K-steps): thread covers 2 chunks per matrix
  const int c0 = wave * 64 + lane;        // chunks [0,256)
  const int c1 = 256 + wave * 64 + lane;  // chunks [256,512)
  const int db0 = (wave * 64) * 8, db1 = (256 + wave * 64) * 8;  // wave-uniform dests
  const unsigned short* sA0 = A + (size_t)(rowBase + (c0 & 127)) * D_ + (c0 >> 7) * 8;
  const unsigned short* sA1 = A + (size_t)(rowBase + (c1 & 127)) * D_ + (c1 >> 7) * 8;
  const unsigned short* sB0 = B + (size_t)(colBase + (c0 & 127)) * D_ + (c0 >> 7) * 8;
  const unsigned short* sB1 = B + (size_t)(colBase + (c1 & 127)) * D_ + (c1 >> 7) * 8;

  // prologue: stage steps 0,1 into slots 0,1 (8 loads in flight)
#pragma unroll
  for (int p = 0; p < 2; ++p) {
    const int kk = p * BK;
    gload16(sA0 + kk, &AS[p][db0]);
    gload16(sA1 + kk, &AS[p][db1]);
    gload16(sB0 + kk, &BS[p][db0]);
    gload16(sB1 + kk, &BS[p][db1]);
  }

  f32x4 acc[4][4] = {};
  const int aoff = g * 1024 + (wr * 64 + fr) * 8;  // + m*128 (elems)
  const int boff = g * 1024 + (wc * 64 + fr) * 8;  // + n*128

  int cur = 0;  // slot of step u; prefetch slot = (cur+2)%3
  for (int u = 0; u < NSTEP; ++u) {
    SBAR();  // all waves done reading slot that prefetch will overwrite
    {
      const int su = (u + 2 < NSTEP) ? u + 2 : NSTEP - 1;  // tail: clamped dummy restage
      const int kk = su * BK;
      int sl = cur + 2;
      if (sl >= 3) sl -= 3;
      unsigned short* as_ = AS[sl];
      unsigned short* bs_ = BS[sl];
      gload16(sA0 + kk, as_ + db0);
      gload16(sA1 + kk, as_ + db1);
      gload16(sB0 + kk, bs_ + db0);
      gload16(sB1 + kk, bs_ + db1);
    }
    VMWAIT8();  // step u's 4 chunks landed; u+1/u+2 (8 loads) stay in flight
    SBAR();     // every wave's step-u chunks landed: slot cur fully valid
    const unsigned short* as_ = AS[cur];
    const unsigned short* bs_ = BS[cur];
    bf16x8 af[4], bfr[4];
#pragma unroll
    for (int m = 0; m < 4; ++m) af[m] = *(const bf16x8*)&as_[aoff + m * 128];
#pragma unroll
    for (int n = 0; n < 4; ++n) bfr[n] = *(const bf16x8*)&bs_[boff + n * 128];
    __builtin_amdgcn_s_setprio(1);
#pragma unroll
    for (int m = 0; m < 4; ++m)
#pragma unroll
      for (int n = 0; n < 4; ++n)
        acc[m][n] = __builtin_amdgcn_mfma_f32_16x16x32_bf16(af[m], bfr[n], acc[m][n], 0, 0, 0);
    __builtin_amdgcn_s_setprio(0);
    LGKM0();  // my ds_reads of slot cur drained before next top barrier
    cur = (cur == 2) ? 0 : cur + 1;
  }

  const float scale = 14.285714285714286f;  // 1/0.07
  float sPart = 0.f;
  float colAcc[4] = {0.f, 0.f, 0.f, 0.f};
#pragma unroll
  for (int m = 0; m < 4; ++m) {
    float ra[4] = {0.f, 0.f, 0.f, 0.f};
#pragma unroll
    for (int n = 0; n < 4; ++n) {
      int col = wc * 64 + n * 16 + fr;
      int lc = labC[col];
#pragma unroll
      for (int r = 0; r < 4; ++r) {
        float v = acc[m][n][r] * scale;
        float e = __expf(v);
        ra[r] += e;
        colAcc[n] += e;
        int row = wr * 64 + m * 16 + g * 4 + r;
        if (labR[row] == lc) sPart += v;
      }
    }
#pragma unroll
    for (int r = 0; r < 4; ++r) {
      float x = ra[r];
      x += __shfl_xor(x, 1);
      x += __shfl_xor(x, 2);
      x += __shfl_xor(x, 4);
      x += __shfl_xor(x, 8);
      if (fr == 0) rbuf[wc][wr * 64 + m * 16 + g * 4 + r] = x;
    }
  }
#pragma unroll
  for (int n = 0; n < 4; ++n) {
    float x = colAcc[n];
    x += __shfl_xor(x, 16);
    x += __shfl_xor(x, 32);
    if (g == 0) cbuf[wr][wc * 64 + n * 16 + fr] = x;
  }
  float s = sPart;
#pragma unroll
  for (int m = 32; m; m >>= 1) s += __shfl_xor(s, m);
  if (lane == 0) sbuf[wave] = s;
  __syncthreads();
  if (tid < BM)
    row_part[(size_t)bx * N_ + rowBase + tid] = rbuf[0][tid] + rbuf[1][tid];
  else
    col_part[(size_t)by * N_ + colBase + (tid - BM)] = cbuf[0][tid - BM] + cbuf[1][tid - BM];
  if (tid == 0) S_part[by * 32 + bx] = sbuf[0] + sbuf[1] + sbuf[2] + sbuf[3];
}

// Per-block local histogram; partials out (no atomics, no memset needed)
__global__ __launch_bounds__(256) void reduce_kernel(
    const float* __restrict__ row_part, const float* __restrict__ col_part,
    const float* __restrict__ S_part, const int* __restrict__ labels,
    double* __restrict__ partials) {
  __shared__ int hist[NCLS];
  int tid = threadIdx.x;
  if (tid < NCLS) hist[tid] = 0;
  __syncthreads();
  for (int j = tid; j < N_; j += 256) atomicAdd(&hist[labels[j]], 1);
  __syncthreads();

  int i = blockIdx.x * 256 + tid;  // 0..4095
  float rs = 0.f, cs = 0.f;
#pragma unroll
  for (int b = 0; b < 32; ++b) {
    rs += row_part[(size_t)b * N_ + i];
    cs += col_part[(size_t)b * N_ + i];
  }
  int cnt = hist[labels[i]];
  double term = (double)cnt * ((double)logf(rs) + (double)logf(cs));
  double sterm = (i < 1024) ? (double)S_part[i] : 0.0;
#pragma unroll
  for (int m = 32; m; m >>= 1) {
    term += __shfl_xor(term, m);
    sterm += __shfl_xor(sterm, m);
  }
  __shared__ double tbuf[4], sb[4];
  int lane = tid & 63, w = tid >> 6;
  if (lane == 0) { tbuf[w] = term; sb[w] = sterm; }
  __syncthreads();
  if (tid == 0) {
    partials[blockIdx.x] = tbuf[0] + tbuf[1] + tbuf[2] + tbuf[3];
    partials[16 + blockIdx.x] = sb[0] + sb[1] + sb[2] + sb[3];
  }
}

__global__ void final_kernel(const double* __restrict__ partials, float* __restrict__ out) {
  double t = 0.0, s = 0.0;
#pragma unroll
  for (int i = 0; i < 16; ++i) {
    t += partials[i];
    s += partials[16 + i];
  }
  out[0] = (float)((t - 2.0 * s) / (2.0 * (double)N_));
}

extern "C" void kernel_launch(void* const* d_in, const int* in_sizes, int n_in,
                              void* d_out, int out_size, void* d_ws, size_t ws_size,
                              hipStream_t stream) {
  const float* img = (const float*)d_in[0];
  const float* txt = (const float*)d_in[1];
  const int* labels = (const int*)d_in[2];
  float* out = (float*)d_out;
  char* ws = (char*)d_ws;

  // workspace layout (bytes)
  __hip_bfloat16* img_nb = (__hip_bfloat16*)(ws);             //  6,291,456
  __hip_bfloat16* txt_nb = (__hip_bfloat16*)(ws + 6291456);   //  6,291,456
  float* row_part = (float*)(ws + 12582912);                  //    524,288 (32 x 4096)
  float* col_part = (float*)(ws + 13107200);                  //    524,288
  float* S_part = (float*)(ws + 13631488);                    //      4,096
  double* partials = (double*)(ws + 13635584);                //        256

  normalize_kernel<<<2 * N_, 192, 0, stream>>>(img, txt, img_nb, txt_nb);
  gemm_epi_kernel<<<dim3(32, 32), 256, 0, stream>>>(
      (const unsigned short*)img_nb, (const unsigned short*)txt_nb, labels,
      row_part, col_part, S_part);
  reduce_kernel<<<16, 256, 0, stream>>>(row_part, col_part, S_part, labels, partials);
  final_kernel<<<1, 1, 0, stream>>>(partials, out);
}

// Round 7
// 61.568 us; speedup vs baseline: 1.7673x; 1.3603x over previous
//
#include <hip/hip_runtime.h>
#include <hip/hip_bf16.h>

#define N_ 4096
#define D_ 768
#define NCLS 128
#define BM 128
#define BN 128
#define BK 64
#define NSTEP 12  // D_/BK

typedef __bf16 bf16x8 __attribute__((ext_vector_type(8)));
typedef float f32x4 __attribute__((ext_vector_type(4)));
typedef short s16x8 __attribute__((ext_vector_type(8)));

// Normalize both embedding matrices (blocks [0,N) -> img, [N,2N) -> txt).
__global__ __launch_bounds__(192) void normalize_kernel(
    const float* __restrict__ img, const float* __restrict__ txt,
    __hip_bfloat16* __restrict__ img_nb, __hip_bfloat16* __restrict__ txt_nb) {
  int b = blockIdx.x;
  const float* s;
  __hip_bfloat16* d;
  if (b < N_) {
    s = img + (size_t)b * D_;
    d = img_nb + (size_t)b * D_;
  } else {
    s = txt + (size_t)(b - N_) * D_;
    d = txt_nb + (size_t)(b - N_) * D_;
  }
  int tid = threadIdx.x;
  float4 v = ((const float4*)s)[tid];
  float ss = v.x * v.x + v.y * v.y + v.z * v.z + v.w * v.w;
#pragma unroll
  for (int m = 32; m; m >>= 1) ss += __shfl_xor(ss, m);
  __shared__ float wsum[3];
  int lane = tid & 63, w = tid >> 6;
  if (lane == 0) wsum[w] = ss;
  __syncthreads();
  float inv = 1.0f / fmaxf(sqrtf(wsum[0] + wsum[1] + wsum[2]), 1e-8f);
  ushort4 o;
  o.x = __bfloat16_as_ushort(__float2bfloat16(v.x * inv));
  o.y = __bfloat16_as_ushort(__float2bfloat16(v.y * inv));
  o.z = __bfloat16_as_ushort(__float2bfloat16(v.z * inv));
  o.w = __bfloat16_as_ushort(__float2bfloat16(v.w * inv));
  ((ushort4*)d)[tid] = o;
}

// 128x128-tile GEMM, BK=64 (12 steps, 32 MFMA per barrier pair), VGPR staging
// (r1-style: compiler software-pipelines global loads across the barriers),
// XOR-swizzled LDS chunk layout pos(row,g)=row*8+(g^(row&7)) -- conflict-free
// on both ds_write_b128 (write groups = (t&7)^((t>>3)&7), even) and
// ds_read_b128 (read groups = g^(fr&7), even). Coalesced staging: lanes 0-7
// cover one row's contiguous 128B (16 lines/instr vs 64 in r1-r6).
__global__ __launch_bounds__(256) void gemm_epi_kernel(
    const unsigned short* __restrict__ A, const unsigned short* __restrict__ B,
    const int* __restrict__ labels, float* __restrict__ row_part,
    float* __restrict__ col_part, float* __restrict__ S_part) {
  __shared__ __align__(16) unsigned short As[8192];  // 128 rows x 8 chunks x 8 elems
  __shared__ __align__(16) unsigned short Bs[8192];
  __shared__ int labR[BM], labC[BN];
  __shared__ float rbuf[2][BM], cbuf[2][BN];
  __shared__ float sbuf[4];

  const int bx = blockIdx.x, by = blockIdx.y;
  const int tid = threadIdx.x;
  const int lane = tid & 63, wave = tid >> 6;
  const int wr = wave >> 1, wc = wave & 1;
  const int g = lane >> 4, fr = lane & 15;
  const int rowBase = by * BM, colBase = bx * BN;

  if (tid < BM) labR[tid] = labels[rowBase + tid];
  else labC[tid - BM] = labels[colBase + tid - BM];

  // staging: thread t covers chunk col gq=t&7, rows rbase+32j (j=0..3)
  const int gq = tid & 7, rbase = tid >> 3;  // rbase 0..31
  const unsigned short* pa = A + (size_t)(rowBase + rbase) * D_ + gq * 8;
  const unsigned short* pb = B + (size_t)(colBase + rbase) * D_ + gq * 8;
  // LDS write chunk position for j=0 (ushort index); +j*2048 for rows +32j
  const int wpos = (rbase * 8 + (gq ^ (rbase & 7))) * 8;

  f32x4 acc[4][4] = {};

  for (int u = 0; u < NSTEP; ++u) {
    const int k0 = u * BK;
    s16x8 ra[4], rb[4];
#pragma unroll
    for (int j = 0; j < 4; ++j) {
      ra[j] = *(const s16x8*)(pa + (size_t)(32 * j) * D_ + k0);
      rb[j] = *(const s16x8*)(pb + (size_t)(32 * j) * D_ + k0);
    }
    __syncthreads();  // all waves done reading LDS from previous step
#pragma unroll
    for (int j = 0; j < 4; ++j) {
      *(s16x8*)&As[wpos + j * 2048] = ra[j];
      *(s16x8*)&Bs[wpos + j * 2048] = rb[j];
    }
    __syncthreads();  // tile resident
#pragma unroll
    for (int ks = 0; ks < 2; ++ks) {
      // frag chunk col = ks*4+g, row' = wr*64+m*16+fr; row'&7 == fr&7
      const int sw = (ks * 4 + g) ^ (fr & 7);
      bf16x8 af[4], bf[4];
#pragma unroll
      for (int m = 0; m < 4; ++m)
        af[m] = *(const bf16x8*)&As[((wr * 64 + m * 16 + fr) * 8 + sw) * 8];
#pragma unroll
      for (int n = 0; n < 4; ++n)
        bf[n] = *(const bf16x8*)&Bs[((wc * 64 + n * 16 + fr) * 8 + sw) * 8];
#pragma unroll
      for (int m = 0; m < 4; ++m)
#pragma unroll
        for (int n = 0; n < 4; ++n)
          acc[m][n] = __builtin_amdgcn_mfma_f32_16x16x32_bf16(af[m], bf[n], acc[m][n], 0, 0, 0);
    }
  }
  __syncthreads();

  const float scale = 14.285714285714286f;  // 1/0.07
  float sPart = 0.f;
  float colAcc[4] = {0.f, 0.f, 0.f, 0.f};
#pragma unroll
  for (int m = 0; m < 4; ++m) {
    float ra2[4] = {0.f, 0.f, 0.f, 0.f};
#pragma unroll
    for (int n = 0; n < 4; ++n) {
      int col = wc * 64 + n * 16 + fr;
      int lc = labC[col];
#pragma unroll
      for (int r = 0; r < 4; ++r) {
        float v = acc[m][n][r] * scale;
        float e = __expf(v);
        ra2[r] += e;
        colAcc[n] += e;
        int row = wr * 64 + m * 16 + g * 4 + r;
        if (labR[row] == lc) sPart += v;
      }
    }
#pragma unroll
    for (int r = 0; r < 4; ++r) {
      float x = ra2[r];
      x += __shfl_xor(x, 1);
      x += __shfl_xor(x, 2);
      x += __shfl_xor(x, 4);
      x += __shfl_xor(x, 8);
      if (fr == 0) rbuf[wc][wr * 64 + m * 16 + g * 4 + r] = x;
    }
  }
#pragma unroll
  for (int n = 0; n < 4; ++n) {
    float x = colAcc[n];
    x += __shfl_xor(x, 16);
    x += __shfl_xor(x, 32);
    if (g == 0) cbuf[wr][wc * 64 + n * 16 + fr] = x;
  }
  float s = sPart;
#pragma unroll
  for (int m = 32; m; m >>= 1) s += __shfl_xor(s, m);
  if (lane == 0) sbuf[wave] = s;
  __syncthreads();
  if (tid < BM)
    row_part[(size_t)bx * N_ + rowBase + tid] = rbuf[0][tid] + rbuf[1][tid];
  else
    col_part[(size_t)by * N_ + colBase + (tid - BM)] = cbuf[0][tid - BM] + cbuf[1][tid - BM];
  if (tid == 0) S_part[by * 32 + bx] = sbuf[0] + sbuf[1] + sbuf[2] + sbuf[3];
}

// Per-block local histogram; partials out (no atomics, no memset needed)
__global__ __launch_bounds__(256) void reduce_kernel(
    const float* __restrict__ row_part, const float* __restrict__ col_part,
    const float* __restrict__ S_part, const int* __restrict__ labels,
    double* __restrict__ partials) {
  __shared__ int hist[NCLS];
  int tid = threadIdx.x;
  if (tid < NCLS) hist[tid] = 0;
  __syncthreads();
  for (int j = tid; j < N_; j += 256) atomicAdd(&hist[labels[j]], 1);
  __syncthreads();

  int i = blockIdx.x * 256 + tid;  // 0..4095
  float rs = 0.f, cs = 0.f;
#pragma unroll
  for (int b = 0; b < 32; ++b) {
    rs += row_part[(size_t)b * N_ + i];
    cs += col_part[(size_t)b * N_ + i];
  }
  int cnt = hist[labels[i]];
  double term = (double)cnt * ((double)logf(rs) + (double)logf(cs));
  double sterm = (i < 1024) ? (double)S_part[i] : 0.0;
#pragma unroll
  for (int m = 32; m; m >>= 1) {
    term += __shfl_xor(term, m);
    sterm += __shfl_xor(sterm, m);
  }
  __shared__ double tbuf[4], sb[4];
  int lane = tid & 63, w = tid >> 6;
  if (lane == 0) { tbuf[w] = term; sb[w] = sterm; }
  __syncthreads();
  if (tid == 0) {
    partials[blockIdx.x] = tbuf[0] + tbuf[1] + tbuf[2] + tbuf[3];
    partials[16 + blockIdx.x] = sb[0] + sb[1] + sb[2] + sb[3];
  }
}

__global__ void final_kernel(const double* __restrict__ partials, float* __restrict__ out) {
  double t = 0.0, s = 0.0;
#pragma unroll
  for (int i = 0; i < 16; ++i) {
    t += partials[i];
    s += partials[16 + i];
  }
  out[0] = (float)((t - 2.0 * s) / (2.0 * (double)N_));
}

extern "C" void kernel_launch(void* const* d_in, const int* in_sizes, int n_in,
                              void* d_out, int out_size, void* d_ws, size_t ws_size,
                              hipStream_t stream) {
  const float* img = (const float*)d_in[0];
  const float* txt = (const float*)d_in[1];
  const int* labels = (const int*)d_in[2];
  float* out = (float*)d_out;
  char* ws = (char*)d_ws;

  // workspace layout (bytes)
  __hip_bfloat16* img_nb = (__hip_bfloat16*)(ws);             //  6,291,456
  __hip_bfloat16* txt_nb = (__hip_bfloat16*)(ws + 6291456);   //  6,291,456
  float* row_part = (float*)(ws + 12582912);                  //    524,288 (32 x 4096)
  float* col_part = (float*)(ws + 13107200);                  //    524,288
  float* S_part = (float*)(ws + 13631488);                    //      4,096
  double* partials = (double*)(ws + 13635584);                //        256

  normalize_kernel<<<2 * N_, 192, 0, stream>>>(img, txt, img_nb, txt_nb);
  gemm_epi_kernel<<<dim3(32, 32), 256, 0, stream>>>(
      (const unsigned short*)img_nb, (const unsigned short*)txt_nb, labels,
      row_part, col_part, S_part);
  reduce_kernel<<<16, 256, 0, stream>>>(row_part, col_part, S_part, labels, partials);
  final_kernel<<<1, 1, 0, stream>>>(partials, out);
}